// Round 1
// baseline (1316.682 us; speedup 1.0000x reference)
//
#include <hip/hip_runtime.h>
#include <hip/hip_bf16.h>

typedef unsigned short u16;
typedef __attribute__((ext_vector_type(8))) short short8;
typedef __attribute__((ext_vector_type(4))) float floatx4;

#define DI __device__ __forceinline__

constexpr int Tn  = 2048;
constexpr int En  = 1024;
constexpr int BTn = 4096;   // B*T

DI float bf2f(u16 u) { union { unsigned int i; float f; } v; v.i = (unsigned int)u << 16; return v.f; }
DI u16 f2bf(float f) {
  union { float f; unsigned int i; } u; u.f = f;
  unsigned int r = u.i + 0x7FFFu + ((u.i >> 16) & 1u);
  return (u16)(r >> 16);
}
DI float gelu_f(float x) { return 0.5f * x * (1.f + erff(x * 0.70710678118654752f)); }
DI float sigmoid_f(float x) { return 1.f / (1.f + __expf(-x)); }

// async global->LDS, 16 bytes per lane. LDS dest must be wave-uniform base +
// lane*16 (all call sites below have LDS byte offset == 16*tid, which is
// exactly that pattern).
DI void gload_lds16(const u16* g, u16* l) {
  __builtin_amdgcn_global_load_lds(
      (const __attribute__((address_space(1))) unsigned int*)g,
      (__attribute__((address_space(3))) unsigned int*)l, 16, 0, 0);
}

// ---------------------------------------------------------------------------
// GEMM: C[M,N] = A[M,K] * Bt[N,K]^T (+bias fp32) (+epilogue). A,Bt,C bf16,
// fp32 accum. EPI: 0=none, 1=gelu, 2=sigmoid. M%128==0, N%128==0, K%32==0.
// m97 structure: 128x128 tile, BK=32, global_load_lds width-16 staging.
// ---------------------------------------------------------------------------
template <int EPI>
__launch_bounds__(256, 2)
__global__ void gemm_bt(const u16* __restrict__ A, const u16* __restrict__ Bt,
                        const float* __restrict__ bias, u16* __restrict__ C,
                        int M, int N, int K) {
  __shared__ __align__(16) u16 As[128 * 32];
  __shared__ __align__(16) u16 Bs[128 * 32];
  const int tid = threadIdx.x;
  const int m0 = blockIdx.y << 7, n0 = blockIdx.x << 7;
  const int lane = tid & 63, l15 = lane & 15, quad = lane >> 4;
  const int wave = tid >> 6;
  const int wm = (wave >> 1) << 6, wn = (wave & 1) << 6;

  const int ra = tid >> 2, c8 = (tid & 3) << 3;
  const u16* pa0 = A + (size_t)(m0 + ra) * K + c8;
  const u16* pa1 = pa0 + (size_t)64 * K;
  const u16* pb0 = Bt + (size_t)(n0 + ra) * K + c8;
  const u16* pb1 = pb0 + (size_t)64 * K;
  u16* sA0 = &As[ra * 32 + c8]; u16* sA1 = &As[(ra + 64) * 32 + c8];
  u16* sB0 = &Bs[ra * 32 + c8]; u16* sB1 = &Bs[(ra + 64) * 32 + c8];

  floatx4 acc[4][4] = {};
  for (int k0 = 0; k0 < K; k0 += 32) {
    gload_lds16(pa0 + k0, sA0);
    gload_lds16(pa1 + k0, sA1);
    gload_lds16(pb0 + k0, sB0);
    gload_lds16(pb1 + k0, sB1);
    __syncthreads();
    short8 af[4], bfr[4];
#pragma unroll
    for (int i = 0; i < 4; ++i) {
      af[i]  = *(const short8*)&As[(wm + i * 16 + l15) * 32 + quad * 8];
      bfr[i] = *(const short8*)&Bs[(wn + i * 16 + l15) * 32 + quad * 8];
    }
#pragma unroll
    for (int i = 0; i < 4; ++i)
#pragma unroll
      for (int j = 0; j < 4; ++j)
        acc[i][j] = __builtin_amdgcn_mfma_f32_16x16x32_bf16(af[i], bfr[j], acc[i][j], 0, 0, 0);
    __syncthreads();
  }
#pragma unroll
  for (int j = 0; j < 4; ++j) {
    const int col = n0 + wn + j * 16 + l15;
    const float bv = bias ? bias[col] : 0.f;
#pragma unroll
    for (int i = 0; i < 4; ++i) {
#pragma unroll
      for (int r = 0; r < 4; ++r) {
        const int row = m0 + wm + i * 16 + quad * 4 + r;
        float v = acc[i][j][r] + bv;
        if (EPI == 1) v = gelu_f(v);
        if (EPI == 2) v = sigmoid_f(v);
        C[(size_t)row * N + col] = f2bf(v);
      }
    }
  }
}

// ---------------------------------------------------------------------------
// Attention scores: P~ = exp(q k^T / 8) causal (0 above diag), unnormalized,
// fp32, written into the wei output area. Row sums into lsum (atomic).
// grid: (n_tiles=16, m_tiles=16, bh=32)
// ---------------------------------------------------------------------------
__launch_bounds__(256, 2)
__global__ void attn_scores(const u16* __restrict__ qkv, float* __restrict__ wei,
                            float* __restrict__ lsum) {
  const int bh = blockIdx.z, b = bh >> 4, h = bh & 15;
  const int m0 = blockIdx.y << 7, n0 = blockIdx.x << 7;
  float* weib = wei + (size_t)bh * Tn * Tn;
  const int tid = threadIdx.x;
  if (n0 > m0 + 127) {               // fully masked block -> zeros
    const float4 z = {0.f, 0.f, 0.f, 0.f};
#pragma unroll
    for (int it = 0; it < 16; ++it) {
      int lin = it * 256 + tid;
      int r = lin >> 5, c4 = (lin & 31) << 2;
      *(float4*)&weib[(size_t)(m0 + r) * Tn + n0 + c4] = z;
    }
    return;
  }
  __shared__ __align__(16) u16 Qs[128 * 64];
  __shared__ __align__(16) u16 Ks[128 * 64];
  const int lane = tid & 63, l15 = lane & 15, quad = lane >> 4;
  const int wave = tid >> 6;
  const int wm = (wave >> 1) << 6, wn = (wave & 1) << 6;
  const u16* qb = qkv + (size_t)b * Tn * 3072 + h * 64;
  const u16* kb = qb + 1024;
#pragma unroll
  for (int it = 0; it < 4; ++it) {
    int lin = it * 256 + tid;
    int r = lin >> 3, cc = (lin & 7) << 3;
    gload_lds16(&qb[(size_t)(m0 + r) * 3072 + cc], &Qs[r * 64 + cc]);
    gload_lds16(&kb[(size_t)(n0 + r) * 3072 + cc], &Ks[r * 64 + cc]);
  }
  __syncthreads();
  floatx4 acc[4][4] = {};
#pragma unroll
  for (int ks = 0; ks < 2; ++ks) {
    short8 af[4], bfr[4];
#pragma unroll
    for (int i = 0; i < 4; ++i) {
      af[i]  = *(const short8*)&Qs[(wm + i * 16 + l15) * 64 + ks * 32 + quad * 8];
      bfr[i] = *(const short8*)&Ks[(wn + i * 16 + l15) * 64 + ks * 32 + quad * 8];
    }
#pragma unroll
    for (int i = 0; i < 4; ++i)
#pragma unroll
      for (int j = 0; j < 4; ++j)
        acc[i][j] = __builtin_amdgcn_mfma_f32_16x16x32_bf16(af[i], bfr[j], acc[i][j], 0, 0, 0);
  }
#pragma unroll
  for (int i = 0; i < 4; ++i) {
#pragma unroll
    for (int r = 0; r < 4; ++r) {
      const int row = m0 + wm + i * 16 + quad * 4 + r;
      float ps = 0.f;
#pragma unroll
      for (int j = 0; j < 4; ++j) {
        const int col = n0 + wn + j * 16 + l15;
        float p = (col <= row) ? __expf(acc[i][j][r] * 0.125f) : 0.f;
        weib[(size_t)row * Tn + col] = p;
        ps += p;
      }
      float v = ps;
      v += __shfl_xor(v, 1); v += __shfl_xor(v, 2);
      v += __shfl_xor(v, 4); v += __shfl_xor(v, 8);
      if (l15 == 0) atomicAdd(&lsum[bh * Tn + row], v);
    }
  }
}

// ---------------------------------------------------------------------------
// PV: attn = (P~/l) @ v. Normalizes P~ -> wei (fp32) in place while staging
// bf16 A tiles. Causal: k-loop to m0+128. grid: (m_tiles=16, 1, bh=32).
// ---------------------------------------------------------------------------
__launch_bounds__(256, 2)
__global__ void attn_pv(float* __restrict__ wei, const u16* __restrict__ vT,
                        const float* __restrict__ lsum, u16* __restrict__ attn_out) {
  const int bh = blockIdx.z, b = bh >> 4, h = bh & 15;
  const int m0 = blockIdx.x << 7;
  float* weib = wei + (size_t)bh * Tn * Tn;
  const u16* vtb = vT + (size_t)bh * 64 * Tn;
  __shared__ __align__(16) u16 Ps[128 * 32];
  __shared__ __align__(16) u16 Vs[64 * 32];
  const int tid = threadIdx.x;
  const int lane = tid & 63, l15 = lane & 15, quad = lane >> 4;
  const int wave = tid >> 6;
  const int ra = tid >> 2, c8 = (tid & 3) << 3;
  const float inv0 = 1.f / lsum[bh * Tn + m0 + ra];
  const float inv1 = 1.f / lsum[bh * Tn + m0 + ra + 64];
  floatx4 acc[2][4] = {};
  const int kmax = m0 + 128;
  for (int k0 = 0; k0 < kmax; k0 += 32) {
    gload_lds16(&vtb[(size_t)ra * Tn + k0 + c8], &Vs[ra * 32 + c8]);
#pragma unroll
    for (int half = 0; half < 2; ++half) {
      const int r = ra + half * 64;
      const float inv = half ? inv1 : inv0;
      size_t go = (size_t)(m0 + r) * Tn + k0 + c8;
      float4 a = *(float4*)&weib[go];
      float4 b4 = *(float4*)&weib[go + 4];
      a.x *= inv; a.y *= inv; a.z *= inv; a.w *= inv;
      b4.x *= inv; b4.y *= inv; b4.z *= inv; b4.w *= inv;
      u16 o8[8] = { f2bf(a.x), f2bf(a.y), f2bf(a.z), f2bf(a.w),
                    f2bf(b4.x), f2bf(b4.y), f2bf(b4.z), f2bf(b4.w) };
      *(uint4*)&Ps[r * 32 + c8] = *(uint4*)o8;
      *(float4*)&weib[go] = a;           // normalized wei back to output
      *(float4*)&weib[go + 4] = b4;
    }
    __syncthreads();
    short8 af[2], bfr[4];
#pragma unroll
    for (int i = 0; i < 2; ++i)
      af[i] = *(const short8*)&Ps[(wave * 32 + i * 16 + l15) * 32 + quad * 8];
#pragma unroll
    for (int j = 0; j < 4; ++j)
      bfr[j] = *(const short8*)&Vs[(j * 16 + l15) * 32 + quad * 8];
#pragma unroll
    for (int i = 0; i < 2; ++i)
#pragma unroll
      for (int j = 0; j < 4; ++j)
        acc[i][j] = __builtin_amdgcn_mfma_f32_16x16x32_bf16(af[i], bfr[j], acc[i][j], 0, 0, 0);
    __syncthreads();
  }
#pragma unroll
  for (int i = 0; i < 2; ++i)
#pragma unroll
    for (int j = 0; j < 4; ++j)
#pragma unroll
      for (int r = 0; r < 4; ++r) {
        const int row = m0 + wave * 32 + i * 16 + quad * 4 + r;
        const int col = j * 16 + l15;
        attn_out[(size_t)(b * Tn + row) * En + h * 64 + col] = f2bf(acc[i][j][r]);
      }
}

// ---------------------------------------------------------------------------
// 64x64-tiled transpose fp32 -> bf16: out[C][R] = bf16(in[R][C]^T).
// ---------------------------------------------------------------------------
__global__ void transpose_wf(const float* __restrict__ in, u16* __restrict__ out, int R, int Cc) {
  __shared__ u16 t[64][65];
  const int tid = threadIdx.x;
  const int r0 = blockIdx.y << 6, c0 = blockIdx.x << 6;
#pragma unroll
  for (int it = 0; it < 4; ++it) {
    int lin = it * 256 + tid;
    int r = lin >> 4, c4 = (lin & 15) << 2;
    float4 v = *(const float4*)&in[(size_t)(r0 + r) * Cc + c0 + c4];
    t[r][c4 + 0] = f2bf(v.x); t[r][c4 + 1] = f2bf(v.y);
    t[r][c4 + 2] = f2bf(v.z); t[r][c4 + 3] = f2bf(v.w);
  }
  __syncthreads();
#pragma unroll
  for (int it = 0; it < 2; ++it) {
    int lin = it * 256 + tid;
    int r = lin >> 3, cc = (lin & 7) << 3;
    u16 t8[8];
#pragma unroll
    for (int e = 0; e < 8; ++e) t8[e] = t[cc + e][r];
    *(uint4*)&out[(size_t)(c0 + r) * R + r0 + cc] = *(uint4*)t8;
  }
}

// wq/wk/wv fp32 [16][1024][64] -> bf16 WqkvT [3072][1024]
__global__ void repack_qkvw(const float* __restrict__ wq, const float* __restrict__ wk,
                            const float* __restrict__ wv, u16* __restrict__ out) {
  const int which = blockIdx.z;
  const float* w = which == 0 ? wq : (which == 1 ? wk : wv);
  const int h = blockIdx.y;
  const int e0 = blockIdx.x << 6;
  __shared__ u16 t[64][65];
  const int tid = threadIdx.x;
  const float* ib = w + (size_t)h * 1024 * 64;
#pragma unroll
  for (int it = 0; it < 4; ++it) {
    int lin = it * 256 + tid;
    int r = lin >> 4, c4 = (lin & 15) << 2;
    float4 v = *(const float4*)&ib[(size_t)(e0 + r) * 64 + c4];
    t[r][c4 + 0] = f2bf(v.x); t[r][c4 + 1] = f2bf(v.y);
    t[r][c4 + 2] = f2bf(v.z); t[r][c4 + 3] = f2bf(v.w);
  }
  __syncthreads();
  u16* ob = out + ((size_t)which * 1024 + h * 64) * 1024;
#pragma unroll
  for (int it = 0; it < 2; ++it) {
    int lin = it * 256 + tid;
    int r = lin >> 3, cc = (lin & 7) << 3;
    u16 t8[8];
#pragma unroll
    for (int e = 0; e < 8; ++e) t8[e] = t[cc + e][r];
    *(uint4*)&ob[(size_t)r * 1024 + e0 + cc] = *(uint4*)t8;
  }
}

// v slice of qkv (bf16) -> vT [bh][64][T] (bf16)
__global__ void transpose_v(const u16* __restrict__ qkv, u16* __restrict__ vT) {
  const int bh = blockIdx.z, b = bh >> 4, h = bh & 15;
  const int s0 = blockIdx.x << 6;
  __shared__ u16 t[64][65];
  const int tid = threadIdx.x;
  const u16* ib = qkv + (size_t)b * Tn * 3072 + 2048 + h * 64;
#pragma unroll
  for (int it = 0; it < 2; ++it) {
    int lin = it * 256 + tid;
    int r = lin >> 3, cc = (lin & 7) << 3;
    uint4 v = *(const uint4*)&ib[(size_t)(s0 + r) * 3072 + cc];
    u16 t8[8]; *(uint4*)t8 = v;
#pragma unroll
    for (int e = 0; e < 8; ++e) t[r][cc + e] = t8[e];
  }
  __syncthreads();
  u16* ob = vT + (size_t)bh * 64 * Tn;
#pragma unroll
  for (int it = 0; it < 2; ++it) {
    int lin = it * 256 + tid;
    int r = lin >> 3, cc = (lin & 7) << 3;
    u16 t8[8];
#pragma unroll
    for (int e = 0; e < 8; ++e) t8[e] = t[cc + e][r];
    *(uint4*)&ob[(size_t)r * Tn + s0 + cc] = *(uint4*)t8;
  }
}

// fp32 in, fp32 params, bf16 out (GEMM operand)
__launch_bounds__(256)
__global__ void layernorm_k(const float* __restrict__ x, const float* __restrict__ g,
                            const float* __restrict__ be, u16* __restrict__ out) {
  const int row = blockIdx.x;
  const int tid = threadIdx.x;
  const float* xr = x + (size_t)row * En;
  float4 xv = *(const float4*)&xr[tid * 4];
  float s = xv.x + xv.y + xv.z + xv.w;
  float sq = xv.x * xv.x + xv.y * xv.y + xv.z * xv.z + xv.w * xv.w;
#pragma unroll
  for (int o = 1; o < 64; o <<= 1) { s += __shfl_xor(s, o); sq += __shfl_xor(sq, o); }
  __shared__ float red[8];
  const int wave = tid >> 6, lane = tid & 63;
  if (lane == 0) { red[wave] = s; red[wave + 4] = sq; }
  __syncthreads();
  const float S  = red[0] + red[1] + red[2] + red[3];
  const float SQ = red[4] + red[5] + red[6] + red[7];
  const float mu = S * (1.f / 1024.f);
  const float var = SQ * (1.f / 1024.f) - mu * mu;
  const float rstd = rsqrtf(var + 1e-5f);
  float4 gv = *(const float4*)&g[tid * 4];
  float4 bv = *(const float4*)&be[tid * 4];
  ushort4 ov;
  ov.x = f2bf((xv.x - mu) * rstd * gv.x + bv.x);
  ov.y = f2bf((xv.y - mu) * rstd * gv.y + bv.y);
  ov.z = f2bf((xv.z - mu) * rstd * gv.z + bv.z);
  ov.w = f2bf((xv.w - mu) * rstd * gv.w + bv.w);
  *(ushort4*)&out[(size_t)row * En + tid * 4] = ov;
}

// out(fp32) = val(bf16) + gate(bf16) * res(fp32)
__global__ void gated_residual(const u16* __restrict__ val, const u16* __restrict__ gate,
                               const float* __restrict__ res, float* __restrict__ out) {
  const size_t i = ((size_t)blockIdx.x * 256 + threadIdx.x) * 4;
  ushort4 v = *(const ushort4*)&val[i];
  ushort4 g = *(const ushort4*)&gate[i];
  float4 r = *(const float4*)&res[i];
  float4 o;
  o.x = bf2f(v.x) + bf2f(g.x) * r.x;
  o.y = bf2f(v.y) + bf2f(g.y) * r.y;
  o.z = bf2f(v.z) + bf2f(g.z) * r.z;
  o.w = bf2f(v.w) + bf2f(g.w) * r.w;
  *(float4*)&out[i] = o;
}

extern "C" void kernel_launch(void* const* d_in, const int* in_sizes, int n_in,
                              void* d_out, int out_size, void* d_ws, size_t ws_size,
                              hipStream_t stream) {
  const float* x    = (const float*)d_in[0];
  const float* wq   = (const float*)d_in[1];
  const float* wk   = (const float*)d_in[2];
  const float* wv   = (const float*)d_in[3];
  const float* wp   = (const float*)d_in[4];
  const float* bp   = (const float*)d_in[5];
  const float* ln1g = (const float*)d_in[6];
  const float* ln1b = (const float*)d_in[7];
  const float* ln2g = (const float*)d_in[8];
  const float* ln2b = (const float*)d_in[9];
  const float* w1   = (const float*)d_in[10];
  const float* b1   = (const float*)d_in[11];
  const float* w2   = (const float*)d_in[12];
  const float* b2   = (const float*)d_in[13];
  const float* w3   = (const float*)d_in[14];
  const float* b3   = (const float*)d_in[15];
  const float* wga  = (const float*)d_in[16];
  const float* bga  = (const float*)d_in[17];
  const float* wgf  = (const float*)d_in[18];
  const float* bgf  = (const float*)d_in[19];

  float* out_x = (float*)d_out;
  float* wei   = out_x + (size_t)BTn * En;   // output 1, [B,H,T,T] fp32

  char* wsb = (char*)d_ws;
  size_t off = 0;
  auto alloc = [&](size_t bytes) { char* p = wsb + off; off += (bytes + 255) & ~(size_t)255; return p; };
  float* lsum = (float*)alloc((size_t)32 * Tn * 4);
  u16* WqkvT = (u16*)alloc((size_t)3072 * 1024 * 2);
  u16* wpT   = (u16*)alloc((size_t)1024 * 1024 * 2);
  u16* wgaT  = (u16*)alloc((size_t)1024 * 1024 * 2);
  u16* w1T   = (u16*)alloc((size_t)4096 * 1024 * 2);
  u16* w2T   = (u16*)alloc((size_t)2048 * 4096 * 2);
  u16* w3T   = (u16*)alloc((size_t)1024 * 2048 * 2);
  u16* wgfT  = (u16*)alloc((size_t)1024 * 1024 * 2);
  u16* h1    = (u16*)alloc((size_t)BTn * En * 2);      // aliased: h2, g2 later
  u16* qkv   = (u16*)alloc((size_t)BTn * 3072 * 2);    // aliased: f1 start
  u16* vT    = (u16*)alloc((size_t)32 * 64 * Tn * 2);  // aliased: f1 tail
  u16* attn  = (u16*)alloc((size_t)BTn * En * 2);      // aliased: f2 start
  u16* sa    = (u16*)alloc((size_t)BTn * En * 2);      // aliased: f2 tail
  u16* glin  = (u16*)alloc((size_t)BTn * En * 2);      // aliased: f3
  float* x1  = (float*)alloc((size_t)BTn * En * 4);    // fp32 residual stream
  u16* h2 = h1;      // h1 dead after qkv GEMM
  u16* f1 = qkv;     // 32MB = qkv(24MB)+vT(8MB), both dead by then
  u16* f2 = attn;    // 16MB = attn(8MB)+sa(8MB), both dead by then
  u16* f3 = glin;    // glin dead after gated_residual #1
  u16* g2 = h1;      // h1 dead after ff1 GEMM

  hipMemsetAsync(lsum, 0, (size_t)32 * Tn * 4, stream);
  repack_qkvw<<<dim3(16, 16, 3), 256, 0, stream>>>(wq, wk, wv, WqkvT);
  transpose_wf<<<dim3(16, 16), 256, 0, stream>>>(wp,  wpT,  1024, 1024);
  transpose_wf<<<dim3(16, 16), 256, 0, stream>>>(wga, wgaT, 1024, 1024);
  transpose_wf<<<dim3(64, 16), 256, 0, stream>>>(w1,  w1T,  1024, 4096);
  transpose_wf<<<dim3(32, 64), 256, 0, stream>>>(w2,  w2T,  4096, 2048);
  transpose_wf<<<dim3(16, 32), 256, 0, stream>>>(w3,  w3T,  2048, 1024);
  transpose_wf<<<dim3(16, 16), 256, 0, stream>>>(wgf, wgfT, 1024, 1024);

  layernorm_k<<<BTn, 256, 0, stream>>>(x, ln1g, ln1b, h1);
  gemm_bt<0><<<dim3(24, 32), 256, 0, stream>>>(h1, WqkvT, nullptr, qkv, BTn, 3072, 1024);
  transpose_v<<<dim3(32, 1, 32), 256, 0, stream>>>(qkv, vT);
  attn_scores<<<dim3(16, 16, 32), 256, 0, stream>>>(qkv, wei, lsum);
  attn_pv<<<dim3(16, 1, 32), 256, 0, stream>>>(wei, vT, lsum, attn);
  gemm_bt<0><<<dim3(8, 32), 256, 0, stream>>>(attn, wpT, bp, sa, BTn, 1024, 1024);
  gemm_bt<2><<<dim3(8, 32), 256, 0, stream>>>(sa, wgaT, bga, glin, BTn, 1024, 1024);
  gated_residual<<<BTn, 256, 0, stream>>>(sa, glin, x, x1);
  layernorm_k<<<BTn, 256, 0, stream>>>(x1, ln2g, ln2b, h2);
  gemm_bt<1><<<dim3(32, 32), 256, 0, stream>>>(h2, w1T, b1, f1, BTn, 4096, 1024);
  gemm_bt<1><<<dim3(16, 32), 256, 0, stream>>>(f1, w2T, b2, f2, BTn, 2048, 4096);
  gemm_bt<0><<<dim3(8, 32), 256, 0, stream>>>(f2, w3T, b3, f3, BTn, 1024, 2048);
  gemm_bt<2><<<dim3(8, 32), 256, 0, stream>>>(f3, wgfT, bgf, g2, BTn, 1024, 1024);
  gated_residual<<<BTn, 256, 0, stream>>>(f3, g2, x1, out_x);
}

// Round 2
// 1303.961 us; speedup vs baseline: 1.0098x; 1.0098x over previous
//
#include <hip/hip_runtime.h>
#include <hip/hip_bf16.h>

typedef unsigned short u16;
typedef __attribute__((ext_vector_type(8))) short short8;
typedef __attribute__((ext_vector_type(4))) float floatx4;

#define DI __device__ __forceinline__

constexpr int Tn  = 2048;
constexpr int En  = 1024;
constexpr int BTn = 4096;   // B*T

DI float bf2f(u16 u) { union { unsigned int i; float f; } v; v.i = (unsigned int)u << 16; return v.f; }
DI u16 f2bf(float f) {
  union { float f; unsigned int i; } u; u.f = f;
  unsigned int r = u.i + 0x7FFFu + ((u.i >> 16) & 1u);
  return (u16)(r >> 16);
}
DI float gelu_f(float x) { return 0.5f * x * (1.f + erff(x * 0.70710678118654752f)); }
DI float sigmoid_f(float x) { return 1.f / (1.f + __expf(-x)); }

// async global->LDS, 16 bytes per lane. LDS dest must be wave-uniform base +
// lane*16 (all call sites below have LDS byte offset == 16*tid, which is
// exactly that pattern).
DI void gload_lds16(const u16* g, u16* l) {
  __builtin_amdgcn_global_load_lds(
      (const __attribute__((address_space(1))) unsigned int*)g,
      (__attribute__((address_space(3))) unsigned int*)l, 16, 0, 0);
}

// ---------------------------------------------------------------------------
// GEMM: C[M,N] = A[M,K] * Bt[N,K]^T (+bias fp32) (+epilogue). A,Bt,C bf16,
// fp32 accum. EPI: 0=none, 1=gelu, 2=sigmoid. M%128==0, N%128==0, K%96 ok
// (K%32==0, K>=96). 128x128 tile, BK=32.
// Pipelined: 3 LDS buffers, prefetch depth 2, counted vmcnt + raw s_barrier
// (never drains prefetch to 0 in-loop). Critical at 1 block/CU grids (N=1024
// -> 256 wg) where there is no cross-block latency hiding.
// ---------------------------------------------------------------------------
template <int EPI>
__launch_bounds__(256, 2)
__global__ void gemm_bt(const u16* __restrict__ A, const u16* __restrict__ Bt,
                        const float* __restrict__ bias, u16* __restrict__ C,
                        int M, int N, int K) {
  __shared__ __align__(16) u16 As[3][128 * 32];
  __shared__ __align__(16) u16 Bs[3][128 * 32];
  const int tid = threadIdx.x;
  const int m0 = blockIdx.y << 7, n0 = blockIdx.x << 7;
  const int lane = tid & 63, l15 = lane & 15, quad = lane >> 4;
  const int wave = tid >> 6;
  const int wm = (wave >> 1) << 6, wn = (wave & 1) << 6;

  const int ra = tid >> 2, c8 = (tid & 3) << 3;
  const u16* pa0 = A + (size_t)(m0 + ra) * K + c8;
  const u16* pa1 = pa0 + (size_t)64 * K;
  const u16* pb0 = Bt + (size_t)(n0 + ra) * K + c8;
  const u16* pb1 = pb0 + (size_t)64 * K;
  const int lo = ra * 32 + c8;       // LDS elem offset == 16B * tid pattern

  auto STG = [&](int b, int kt) {
    const int ko = kt << 5;
    gload_lds16(pa0 + ko, &As[b][lo]);
    gload_lds16(pa1 + ko, &As[b][lo + 64 * 32]);
    gload_lds16(pb0 + ko, &Bs[b][lo]);
    gload_lds16(pb1 + ko, &Bs[b][lo + 64 * 32]);
  };

  const int nk = K >> 5;             // >= 3 for all call sites
  STG(0, 0); STG(1, 1); STG(2, 2);

  floatx4 acc[4][4] = {};
  int cur = 0;
  for (int k = 0; k < nk; ++k) {
    const int rem = nk - k;
    if (rem > 2)       asm volatile("s_waitcnt vmcnt(8)" ::: "memory");
    else if (rem == 2) asm volatile("s_waitcnt vmcnt(4)" ::: "memory");
    else               asm volatile("s_waitcnt vmcnt(0)" ::: "memory");
    __builtin_amdgcn_s_barrier();          // all waves' tile-k loads landed
    __builtin_amdgcn_sched_barrier(0);
    const u16* Ab = As[cur];
    const u16* Bb = Bs[cur];
    short8 af[4], bfr[4];
#pragma unroll
    for (int i = 0; i < 4; ++i) {
      af[i]  = *(const short8*)&Ab[(wm + i * 16 + l15) * 32 + quad * 8];
      bfr[i] = *(const short8*)&Bb[(wn + i * 16 + l15) * 32 + quad * 8];
    }
#pragma unroll
    for (int i = 0; i < 4; ++i)
#pragma unroll
      for (int j = 0; j < 4; ++j)
        acc[i][j] = __builtin_amdgcn_mfma_f32_16x16x32_bf16(af[i], bfr[j], acc[i][j], 0, 0, 0);
    __builtin_amdgcn_s_barrier();          // all reads of buf[cur] done
    __builtin_amdgcn_sched_barrier(0);
    if (k + 3 < nk) STG(cur, k + 3);       // overwrite now safe
    cur = (cur == 2) ? 0 : cur + 1;
  }
#pragma unroll
  for (int j = 0; j < 4; ++j) {
    const int col = n0 + wn + j * 16 + l15;
    const float bv = bias ? bias[col] : 0.f;
#pragma unroll
    for (int i = 0; i < 4; ++i) {
#pragma unroll
      for (int r = 0; r < 4; ++r) {
        const int row = m0 + wm + i * 16 + quad * 4 + r;
        float v = acc[i][j][r] + bv;
        if (EPI == 1) v = gelu_f(v);
        if (EPI == 2) v = sigmoid_f(v);
        C[(size_t)row * N + col] = f2bf(v);
      }
    }
  }
}

// ---------------------------------------------------------------------------
// Attention scores: P~ = exp(q k^T / 8) causal (0 above diag), unnormalized,
// fp32, written into the wei output area. Row sums into lsum (atomic).
// grid: (n_tiles=16, m_tiles=16, bh=32)
// ---------------------------------------------------------------------------
__launch_bounds__(256, 2)
__global__ void attn_scores(const u16* __restrict__ qkv, float* __restrict__ wei,
                            float* __restrict__ lsum) {
  const int bh = blockIdx.z, b = bh >> 4, h = bh & 15;
  const int m0 = blockIdx.y << 7, n0 = blockIdx.x << 7;
  float* weib = wei + (size_t)bh * Tn * Tn;
  const int tid = threadIdx.x;
  if (n0 > m0 + 127) {               // fully masked block -> zeros
    const float4 z = {0.f, 0.f, 0.f, 0.f};
#pragma unroll
    for (int it = 0; it < 16; ++it) {
      int lin = it * 256 + tid;
      int r = lin >> 5, c4 = (lin & 31) << 2;
      *(float4*)&weib[(size_t)(m0 + r) * Tn + n0 + c4] = z;
    }
    return;
  }
  __shared__ __align__(16) u16 Qs[128 * 64];
  __shared__ __align__(16) u16 Ks[128 * 64];
  const int lane = tid & 63, l15 = lane & 15, quad = lane >> 4;
  const int wave = tid >> 6;
  const int wm = (wave >> 1) << 6, wn = (wave & 1) << 6;
  const u16* qb = qkv + (size_t)b * Tn * 3072 + h * 64;
  const u16* kb = qb + 1024;
#pragma unroll
  for (int it = 0; it < 4; ++it) {
    int lin = it * 256 + tid;
    int r = lin >> 3, cc = (lin & 7) << 3;
    gload_lds16(&qb[(size_t)(m0 + r) * 3072 + cc], &Qs[r * 64 + cc]);
    gload_lds16(&kb[(size_t)(n0 + r) * 3072 + cc], &Ks[r * 64 + cc]);
  }
  __syncthreads();
  floatx4 acc[4][4] = {};
#pragma unroll
  for (int ks = 0; ks < 2; ++ks) {
    short8 af[4], bfr[4];
#pragma unroll
    for (int i = 0; i < 4; ++i) {
      af[i]  = *(const short8*)&Qs[(wm + i * 16 + l15) * 64 + ks * 32 + quad * 8];
      bfr[i] = *(const short8*)&Ks[(wn + i * 16 + l15) * 64 + ks * 32 + quad * 8];
    }
#pragma unroll
    for (int i = 0; i < 4; ++i)
#pragma unroll
      for (int j = 0; j < 4; ++j)
        acc[i][j] = __builtin_amdgcn_mfma_f32_16x16x32_bf16(af[i], bfr[j], acc[i][j], 0, 0, 0);
  }
#pragma unroll
  for (int i = 0; i < 4; ++i) {
#pragma unroll
    for (int r = 0; r < 4; ++r) {
      const int row = m0 + wm + i * 16 + quad * 4 + r;
      float ps = 0.f;
#pragma unroll
      for (int j = 0; j < 4; ++j) {
        const int col = n0 + wn + j * 16 + l15;
        float p = (col <= row) ? __expf(acc[i][j][r] * 0.125f) : 0.f;
        weib[(size_t)row * Tn + col] = p;
        ps += p;
      }
      float v = ps;
      v += __shfl_xor(v, 1); v += __shfl_xor(v, 2);
      v += __shfl_xor(v, 4); v += __shfl_xor(v, 8);
      if (l15 == 0) atomicAdd(&lsum[bh * Tn + row], v);
    }
  }
}

// ---------------------------------------------------------------------------
// PV: attn = (P~/l) @ v. Normalizes P~ -> wei (fp32) in place while staging
// bf16 A tiles. Causal: k-loop to m0+128. grid: (m_tiles=16, 1, bh=32).
// ---------------------------------------------------------------------------
__launch_bounds__(256, 2)
__global__ void attn_pv(float* __restrict__ wei, const u16* __restrict__ vT,
                        const float* __restrict__ lsum, u16* __restrict__ attn_out) {
  const int bh = blockIdx.z, b = bh >> 4, h = bh & 15;
  const int m0 = blockIdx.x << 7;
  float* weib = wei + (size_t)bh * Tn * Tn;
  const u16* vtb = vT + (size_t)bh * 64 * Tn;
  __shared__ __align__(16) u16 Ps[128 * 32];
  __shared__ __align__(16) u16 Vs[64 * 32];
  const int tid = threadIdx.x;
  const int lane = tid & 63, l15 = lane & 15, quad = lane >> 4;
  const int wave = tid >> 6;
  const int ra = tid >> 2, c8 = (tid & 3) << 3;
  const float inv0 = 1.f / lsum[bh * Tn + m0 + ra];
  const float inv1 = 1.f / lsum[bh * Tn + m0 + ra + 64];
  floatx4 acc[2][4] = {};
  const int kmax = m0 + 128;
  for (int k0 = 0; k0 < kmax; k0 += 32) {
    gload_lds16(&vtb[(size_t)ra * Tn + k0 + c8], &Vs[ra * 32 + c8]);
#pragma unroll
    for (int half = 0; half < 2; ++half) {
      const int r = ra + half * 64;
      const float inv = half ? inv1 : inv0;
      size_t go = (size_t)(m0 + r) * Tn + k0 + c8;
      float4 a = *(float4*)&weib[go];
      float4 b4 = *(float4*)&weib[go + 4];
      a.x *= inv; a.y *= inv; a.z *= inv; a.w *= inv;
      b4.x *= inv; b4.y *= inv; b4.z *= inv; b4.w *= inv;
      u16 o8[8] = { f2bf(a.x), f2bf(a.y), f2bf(a.z), f2bf(a.w),
                    f2bf(b4.x), f2bf(b4.y), f2bf(b4.z), f2bf(b4.w) };
      *(uint4*)&Ps[r * 32 + c8] = *(uint4*)o8;
      *(float4*)&weib[go] = a;           // normalized wei back to output
      *(float4*)&weib[go + 4] = b4;
    }
    __syncthreads();
    short8 af[2], bfr[4];
#pragma unroll
    for (int i = 0; i < 2; ++i)
      af[i] = *(const short8*)&Ps[(wave * 32 + i * 16 + l15) * 32 + quad * 8];
#pragma unroll
    for (int j = 0; j < 4; ++j)
      bfr[j] = *(const short8*)&Vs[(j * 16 + l15) * 32 + quad * 8];
#pragma unroll
    for (int i = 0; i < 2; ++i)
#pragma unroll
      for (int j = 0; j < 4; ++j)
        acc[i][j] = __builtin_amdgcn_mfma_f32_16x16x32_bf16(af[i], bfr[j], acc[i][j], 0, 0, 0);
    __syncthreads();
  }
#pragma unroll
  for (int i = 0; i < 2; ++i)
#pragma unroll
    for (int j = 0; j < 4; ++j)
#pragma unroll
      for (int r = 0; r < 4; ++r) {
        const int row = m0 + wave * 32 + i * 16 + quad * 4 + r;
        const int col = j * 16 + l15;
        attn_out[(size_t)(b * Tn + row) * En + h * 64 + col] = f2bf(acc[i][j][r]);
      }
}

// ---------------------------------------------------------------------------
// 64x64-tiled transpose fp32 -> bf16: out[C][R] = bf16(in[R][C]^T).
// ---------------------------------------------------------------------------
__global__ void transpose_wf(const float* __restrict__ in, u16* __restrict__ out, int R, int Cc) {
  __shared__ u16 t[64][65];
  const int tid = threadIdx.x;
  const int r0 = blockIdx.y << 6, c0 = blockIdx.x << 6;
#pragma unroll
  for (int it = 0; it < 4; ++it) {
    int lin = it * 256 + tid;
    int r = lin >> 4, c4 = (lin & 15) << 2;
    float4 v = *(const float4*)&in[(size_t)(r0 + r) * Cc + c0 + c4];
    t[r][c4 + 0] = f2bf(v.x); t[r][c4 + 1] = f2bf(v.y);
    t[r][c4 + 2] = f2bf(v.z); t[r][c4 + 3] = f2bf(v.w);
  }
  __syncthreads();
#pragma unroll
  for (int it = 0; it < 2; ++it) {
    int lin = it * 256 + tid;
    int r = lin >> 3, cc = (lin & 7) << 3;
    u16 t8[8];
#pragma unroll
    for (int e = 0; e < 8; ++e) t8[e] = t[cc + e][r];
    *(uint4*)&out[(size_t)(c0 + r) * R + r0 + cc] = *(uint4*)t8;
  }
}

// wq/wk/wv fp32 [16][1024][64] -> bf16 WqkvT [3072][1024]
__global__ void repack_qkvw(const float* __restrict__ wq, const float* __restrict__ wk,
                            const float* __restrict__ wv, u16* __restrict__ out) {
  const int which = blockIdx.z;
  const float* w = which == 0 ? wq : (which == 1 ? wk : wv);
  const int h = blockIdx.y;
  const int e0 = blockIdx.x << 6;
  __shared__ u16 t[64][65];
  const int tid = threadIdx.x;
  const float* ib = w + (size_t)h * 1024 * 64;
#pragma unroll
  for (int it = 0; it < 4; ++it) {
    int lin = it * 256 + tid;
    int r = lin >> 4, c4 = (lin & 15) << 2;
    float4 v = *(const float4*)&ib[(size_t)(e0 + r) * 64 + c4];
    t[r][c4 + 0] = f2bf(v.x); t[r][c4 + 1] = f2bf(v.y);
    t[r][c4 + 2] = f2bf(v.z); t[r][c4 + 3] = f2bf(v.w);
  }
  __syncthreads();
  u16* ob = out + ((size_t)which * 1024 + h * 64) * 1024;
#pragma unroll
  for (int it = 0; it < 2; ++it) {
    int lin = it * 256 + tid;
    int r = lin >> 3, cc = (lin & 7) << 3;
    u16 t8[8];
#pragma unroll
    for (int e = 0; e < 8; ++e) t8[e] = t[cc + e][r];
    *(uint4*)&ob[(size_t)r * 1024 + e0 + cc] = *(uint4*)t8;
  }
}

// v slice of qkv (bf16) -> vT [bh][64][T] (bf16)
__global__ void transpose_v(const u16* __restrict__ qkv, u16* __restrict__ vT) {
  const int bh = blockIdx.z, b = bh >> 4, h = bh & 15;
  const int s0 = blockIdx.x << 6;
  __shared__ u16 t[64][65];
  const int tid = threadIdx.x;
  const u16* ib = qkv + (size_t)b * Tn * 3072 + 2048 + h * 64;
#pragma unroll
  for (int it = 0; it < 2; ++it) {
    int lin = it * 256 + tid;
    int r = lin >> 3, cc = (lin & 7) << 3;
    uint4 v = *(const uint4*)&ib[(size_t)(s0 + r) * 3072 + cc];
    u16 t8[8]; *(uint4*)t8 = v;
#pragma unroll
    for (int e = 0; e < 8; ++e) t[r][cc + e] = t8[e];
  }
  __syncthreads();
  u16* ob = vT + (size_t)bh * 64 * Tn;
#pragma unroll
  for (int it = 0; it < 2; ++it) {
    int lin = it * 256 + tid;
    int r = lin >> 3, cc = (lin & 7) << 3;
    u16 t8[8];
#pragma unroll
    for (int e = 0; e < 8; ++e) t8[e] = t[cc + e][r];
    *(uint4*)&ob[(size_t)r * Tn + s0 + cc] = *(uint4*)t8;
  }
}

// fp32 in, fp32 params, bf16 out (GEMM operand)
__launch_bounds__(256)
__global__ void layernorm_k(const float* __restrict__ x, const float* __restrict__ g,
                            const float* __restrict__ be, u16* __restrict__ out) {
  const int row = blockIdx.x;
  const int tid = threadIdx.x;
  const float* xr = x + (size_t)row * En;
  float4 xv = *(const float4*)&xr[tid * 4];
  float s = xv.x + xv.y + xv.z + xv.w;
  float sq = xv.x * xv.x + xv.y * xv.y + xv.z * xv.z + xv.w * xv.w;
#pragma unroll
  for (int o = 1; o < 64; o <<= 1) { s += __shfl_xor(s, o); sq += __shfl_xor(sq, o); }
  __shared__ float red[8];
  const int wave = tid >> 6, lane = tid & 63;
  if (lane == 0) { red[wave] = s; red[wave + 4] = sq; }
  __syncthreads();
  const float S  = red[0] + red[1] + red[2] + red[3];
  const float SQ = red[4] + red[5] + red[6] + red[7];
  const float mu = S * (1.f / 1024.f);
  const float var = SQ * (1.f / 1024.f) - mu * mu;
  const float rstd = rsqrtf(var + 1e-5f);
  float4 gv = *(const float4*)&g[tid * 4];
  float4 bv = *(const float4*)&be[tid * 4];
  ushort4 ov;
  ov.x = f2bf((xv.x - mu) * rstd * gv.x + bv.x);
  ov.y = f2bf((xv.y - mu) * rstd * gv.y + bv.y);
  ov.z = f2bf((xv.z - mu) * rstd * gv.z + bv.z);
  ov.w = f2bf((xv.w - mu) * rstd * gv.w + bv.w);
  *(ushort4*)&out[(size_t)row * En + tid * 4] = ov;
}

// out(fp32) = val(bf16) + gate(bf16) * res(fp32)
__global__ void gated_residual(const u16* __restrict__ val, const u16* __restrict__ gate,
                               const float* __restrict__ res, float* __restrict__ out) {
  const size_t i = ((size_t)blockIdx.x * 256 + threadIdx.x) * 4;
  ushort4 v = *(const ushort4*)&val[i];
  ushort4 g = *(const ushort4*)&gate[i];
  float4 r = *(const float4*)&res[i];
  float4 o;
  o.x = bf2f(v.x) + bf2f(g.x) * r.x;
  o.y = bf2f(v.y) + bf2f(g.y) * r.y;
  o.z = bf2f(v.z) + bf2f(g.z) * r.z;
  o.w = bf2f(v.w) + bf2f(g.w) * r.w;
  *(float4*)&out[i] = o;
}

extern "C" void kernel_launch(void* const* d_in, const int* in_sizes, int n_in,
                              void* d_out, int out_size, void* d_ws, size_t ws_size,
                              hipStream_t stream) {
  const float* x    = (const float*)d_in[0];
  const float* wq   = (const float*)d_in[1];
  const float* wk   = (const float*)d_in[2];
  const float* wv   = (const float*)d_in[3];
  const float* wp   = (const float*)d_in[4];
  const float* bp   = (const float*)d_in[5];
  const float* ln1g = (const float*)d_in[6];
  const float* ln1b = (const float*)d_in[7];
  const float* ln2g = (const float*)d_in[8];
  const float* ln2b = (const float*)d_in[9];
  const float* w1   = (const float*)d_in[10];
  const float* b1   = (const float*)d_in[11];
  const float* w2   = (const float*)d_in[12];
  const float* b2   = (const float*)d_in[13];
  const float* w3   = (const float*)d_in[14];
  const float* b3   = (const float*)d_in[15];
  const float* wga  = (const float*)d_in[16];
  const float* bga  = (const float*)d_in[17];
  const float* wgf  = (const float*)d_in[18];
  const float* bgf  = (const float*)d_in[19];

  float* out_x = (float*)d_out;
  float* wei   = out_x + (size_t)BTn * En;   // output 1, [B,H,T,T] fp32

  char* wsb = (char*)d_ws;
  size_t off = 0;
  auto alloc = [&](size_t bytes) { char* p = wsb + off; off += (bytes + 255) & ~(size_t)255; return p; };
  float* lsum = (float*)alloc((size_t)32 * Tn * 4);
  u16* WqkvT = (u16*)alloc((size_t)3072 * 1024 * 2);
  u16* wpT   = (u16*)alloc((size_t)1024 * 1024 * 2);
  u16* wgaT  = (u16*)alloc((size_t)1024 * 1024 * 2);
  u16* w1T   = (u16*)alloc((size_t)4096 * 1024 * 2);
  u16* w2T   = (u16*)alloc((size_t)2048 * 4096 * 2);
  u16* w3T   = (u16*)alloc((size_t)1024 * 2048 * 2);
  u16* wgfT  = (u16*)alloc((size_t)1024 * 1024 * 2);
  u16* h1    = (u16*)alloc((size_t)BTn * En * 2);      // aliased: h2, g2 later
  u16* qkv   = (u16*)alloc((size_t)BTn * 3072 * 2);    // aliased: f1 start
  u16* vT    = (u16*)alloc((size_t)32 * 64 * Tn * 2);  // aliased: f1 tail
  u16* attn  = (u16*)alloc((size_t)BTn * En * 2);      // aliased: f2 start
  u16* sa    = (u16*)alloc((size_t)BTn * En * 2);      // aliased: f2 tail
  u16* glin  = (u16*)alloc((size_t)BTn * En * 2);      // aliased: f3
  float* x1  = (float*)alloc((size_t)BTn * En * 4);    // fp32 residual stream
  u16* h2 = h1;      // h1 dead after qkv GEMM
  u16* f1 = qkv;     // 32MB = qkv(24MB)+vT(8MB), both dead by then
  u16* f2 = attn;    // 16MB = attn(8MB)+sa(8MB), both dead by then
  u16* f3 = glin;    // glin dead after gated_residual #1
  u16* g2 = h1;      // h1 dead after ff1 GEMM

  hipMemsetAsync(lsum, 0, (size_t)32 * Tn * 4, stream);
  repack_qkvw<<<dim3(16, 16, 3), 256, 0, stream>>>(wq, wk, wv, WqkvT);
  transpose_wf<<<dim3(16, 16), 256, 0, stream>>>(wp,  wpT,  1024, 1024);
  transpose_wf<<<dim3(16, 16), 256, 0, stream>>>(wga, wgaT, 1024, 1024);
  transpose_wf<<<dim3(64, 16), 256, 0, stream>>>(w1,  w1T,  1024, 4096);
  transpose_wf<<<dim3(32, 64), 256, 0, stream>>>(w2,  w2T,  4096, 2048);
  transpose_wf<<<dim3(16, 32), 256, 0, stream>>>(w3,  w3T,  2048, 1024);
  transpose_wf<<<dim3(16, 16), 256, 0, stream>>>(wgf, wgfT, 1024, 1024);

  layernorm_k<<<BTn, 256, 0, stream>>>(x, ln1g, ln1b, h1);
  gemm_bt<0><<<dim3(24, 32), 256, 0, stream>>>(h1, WqkvT, nullptr, qkv, BTn, 3072, 1024);
  transpose_v<<<dim3(32, 1, 32), 256, 0, stream>>>(qkv, vT);
  attn_scores<<<dim3(16, 16, 32), 256, 0, stream>>>(qkv, wei, lsum);
  attn_pv<<<dim3(16, 1, 32), 256, 0, stream>>>(wei, vT, lsum, attn);
  gemm_bt<0><<<dim3(8, 32), 256, 0, stream>>>(attn, wpT, bp, sa, BTn, 1024, 1024);
  gemm_bt<2><<<dim3(8, 32), 256, 0, stream>>>(sa, wgaT, bga, glin, BTn, 1024, 1024);
  gated_residual<<<BTn, 256, 0, stream>>>(sa, glin, x, x1);
  layernorm_k<<<BTn, 256, 0, stream>>>(x1, ln2g, ln2b, h2);
  gemm_bt<1><<<dim3(32, 32), 256, 0, stream>>>(h2, w1T, b1, f1, BTn, 4096, 1024);
  gemm_bt<1><<<dim3(16, 32), 256, 0, stream>>>(f1, w2T, b2, f2, BTn, 2048, 4096);
  gemm_bt<0><<<dim3(8, 32), 256, 0, stream>>>(f2, w3T, b3, f3, BTn, 1024, 2048);
  gemm_bt<2><<<dim3(8, 32), 256, 0, stream>>>(f3, wgfT, bgf, g2, BTn, 1024, 1024);
  gated_residual<<<BTn, 256, 0, stream>>>(f3, g2, x1, out_x);
}

// Round 3
// 1125.694 us; speedup vs baseline: 1.1697x; 1.1584x over previous
//
#include <hip/hip_runtime.h>
#include <hip/hip_bf16.h>

typedef unsigned short u16;
typedef __attribute__((ext_vector_type(8))) short short8;
typedef __attribute__((ext_vector_type(4))) float floatx4;

#define DI __device__ __forceinline__

constexpr int Tn  = 2048;
constexpr int En  = 1024;
constexpr int BTn = 4096;   // B*T

DI float bf2f(u16 u) { union { unsigned int i; float f; } v; v.i = (unsigned int)u << 16; return v.f; }
DI u16 f2bf(float f) {
  union { float f; unsigned int i; } u; u.f = f;
  unsigned int r = u.i + 0x7FFFu + ((u.i >> 16) & 1u);
  return (u16)(r >> 16);
}
DI float gelu_f(float x) { return 0.5f * x * (1.f + erff(x * 0.70710678118654752f)); }
DI float sigmoid_f(float x) { return 1.f / (1.f + __expf(-x)); }

// async global->LDS, 16 bytes per lane. LDS dest must be wave-uniform base +
// lane*16 (all call sites below satisfy this: LDS byte offset == 16*tid).
DI void gload_lds16(const u16* g, u16* l) {
  __builtin_amdgcn_global_load_lds(
      (const __attribute__((address_space(1))) unsigned int*)g,
      (__attribute__((address_space(3))) unsigned int*)l, 16, 0, 0);
}

// ---------------------------------------------------------------------------
// GEMM: C[M,N] = A[M,K] * Bt[N,K]^T (+bias fp32) (+epilogue). A,Bt,C bf16,
// fp32 accum. EPI: 0=none, 1=gelu, 2=sigmoid. 128x128 tile, BK=32,
// 3-buffer pipelined, counted vmcnt. (Round-2 version, kept.)
// ---------------------------------------------------------------------------
template <int EPI>
__launch_bounds__(256, 2)
__global__ void gemm_bt(const u16* __restrict__ A, const u16* __restrict__ Bt,
                        const float* __restrict__ bias, u16* __restrict__ C,
                        int M, int N, int K) {
  __shared__ __align__(16) u16 As[3][128 * 32];
  __shared__ __align__(16) u16 Bs[3][128 * 32];
  const int tid = threadIdx.x;
  const int m0 = blockIdx.y << 7, n0 = blockIdx.x << 7;
  const int lane = tid & 63, l15 = lane & 15, quad = lane >> 4;
  const int wave = tid >> 6;
  const int wm = (wave >> 1) << 6, wn = (wave & 1) << 6;

  const int ra = tid >> 2, c8 = (tid & 3) << 3;
  const u16* pa0 = A + (size_t)(m0 + ra) * K + c8;
  const u16* pa1 = pa0 + (size_t)64 * K;
  const u16* pb0 = Bt + (size_t)(n0 + ra) * K + c8;
  const u16* pb1 = pb0 + (size_t)64 * K;
  const int lo = ra * 32 + c8;

  auto STG = [&](int b, int kt) {
    const int ko = kt << 5;
    gload_lds16(pa0 + ko, &As[b][lo]);
    gload_lds16(pa1 + ko, &As[b][lo + 64 * 32]);
    gload_lds16(pb0 + ko, &Bs[b][lo]);
    gload_lds16(pb1 + ko, &Bs[b][lo + 64 * 32]);
  };

  const int nk = K >> 5;
  STG(0, 0); STG(1, 1); STG(2, 2);

  floatx4 acc[4][4] = {};
  int cur = 0;
  for (int k = 0; k < nk; ++k) {
    const int rem = nk - k;
    if (rem > 2)       asm volatile("s_waitcnt vmcnt(8)" ::: "memory");
    else if (rem == 2) asm volatile("s_waitcnt vmcnt(4)" ::: "memory");
    else               asm volatile("s_waitcnt vmcnt(0)" ::: "memory");
    __builtin_amdgcn_s_barrier();
    __builtin_amdgcn_sched_barrier(0);
    const u16* Ab = As[cur];
    const u16* Bb = Bs[cur];
    short8 af[4], bfr[4];
#pragma unroll
    for (int i = 0; i < 4; ++i) {
      af[i]  = *(const short8*)&Ab[(wm + i * 16 + l15) * 32 + quad * 8];
      bfr[i] = *(const short8*)&Bb[(wn + i * 16 + l15) * 32 + quad * 8];
    }
#pragma unroll
    for (int i = 0; i < 4; ++i)
#pragma unroll
      for (int j = 0; j < 4; ++j)
        acc[i][j] = __builtin_amdgcn_mfma_f32_16x16x32_bf16(af[i], bfr[j], acc[i][j], 0, 0, 0);
    __builtin_amdgcn_s_barrier();
    __builtin_amdgcn_sched_barrier(0);
    if (k + 3 < nk) STG(cur, k + 3);
    cur = (cur == 2) ? 0 : cur + 1;
  }
#pragma unroll
  for (int j = 0; j < 4; ++j) {
    const int col = n0 + wn + j * 16 + l15;
    const float bv = bias ? bias[col] : 0.f;
#pragma unroll
    for (int i = 0; i < 4; ++i) {
#pragma unroll
      for (int r = 0; r < 4; ++r) {
        const int row = m0 + wm + i * 16 + quad * 4 + r;
        float v = acc[i][j][r] + bv;
        if (EPI == 1) v = gelu_f(v);
        if (EPI == 2) v = sigmoid_f(v);
        C[(size_t)row * N + col] = f2bf(v);
      }
    }
  }
}

// ---------------------------------------------------------------------------
// Attention pass 1: row sums of exp(qk^T/8) (causal) -> lsum (atomic), and
// zero-fill of the fully-masked upper-triangle wei tiles. NO P~ store.
// grid: (n_tiles=16, m_tiles=16, bh=32). Swizzled LDS (conflict-free).
// ---------------------------------------------------------------------------
__launch_bounds__(256, 2)
__global__ void attn_rowsum(const u16* __restrict__ qkv, float* __restrict__ wei,
                            float* __restrict__ lsum) {
  const int bh = blockIdx.z, b = bh >> 4, h = bh & 15;
  const int m0 = blockIdx.y << 7, n0 = blockIdx.x << 7;
  float* weib = wei + (size_t)bh * Tn * Tn;
  const int tid = threadIdx.x;
  if (n0 > m0 + 127) {               // fully masked block -> zeros
    const float4 z = {0.f, 0.f, 0.f, 0.f};
#pragma unroll
    for (int it = 0; it < 16; ++it) {
      int lin = it * 256 + tid;
      int r = lin >> 5, c4 = (lin & 31) << 2;
      *(float4*)&weib[(size_t)(m0 + r) * Tn + n0 + c4] = z;
    }
    return;
  }
  __shared__ __align__(16) u16 Qs[128 * 64];
  __shared__ __align__(16) u16 Ks[128 * 64];
  const int lane = tid & 63, l15 = lane & 15, quad = lane >> 4;
  const int wave = tid >> 6;
  const int wm = (wave >> 1) << 6, wn = (wave & 1) << 6;
  const u16* qb = qkv + (size_t)b * Tn * 3072 + h * 64;
  const u16* kb = qb + 1024;
#pragma unroll
  for (int it = 0; it < 4; ++it) {
    int lin = it * 256 + tid;
    int r = lin >> 3, cc = (lin & 7) << 3;
    int cs = cc ^ ((r & 7) << 3);            // pre-swizzled global source col
    gload_lds16(&qb[(size_t)(m0 + r) * 3072 + cs], &Qs[r * 64 + cc]);
    gload_lds16(&kb[(size_t)(n0 + r) * 3072 + cs], &Ks[r * 64 + cc]);
  }
  __syncthreads();
  floatx4 acc[4][4] = {};
#pragma unroll
  for (int ks = 0; ks < 2; ++ks) {
    short8 af[4], bfr[4];
#pragma unroll
    for (int i = 0; i < 4; ++i) {
      const int qr = wm + i * 16 + l15;
      const int kr = wn + i * 16 + l15;
      af[i]  = *(const short8*)&Qs[qr * 64 + ((ks * 32 + quad * 8) ^ ((qr & 7) << 3))];
      bfr[i] = *(const short8*)&Ks[kr * 64 + ((ks * 32 + quad * 8) ^ ((kr & 7) << 3))];
    }
#pragma unroll
    for (int i = 0; i < 4; ++i)
#pragma unroll
      for (int j = 0; j < 4; ++j)
        acc[i][j] = __builtin_amdgcn_mfma_f32_16x16x32_bf16(af[i], bfr[j], acc[i][j], 0, 0, 0);
  }
#pragma unroll
  for (int i = 0; i < 4; ++i) {
#pragma unroll
    for (int r = 0; r < 4; ++r) {
      const int row = m0 + wm + i * 16 + quad * 4 + r;
      float ps = 0.f;
#pragma unroll
      for (int j = 0; j < 4; ++j) {
        const int col = n0 + wn + j * 16 + l15;
        float p = (col <= row) ? __expf(acc[i][j][r] * 0.125f) : 0.f;
        ps += p;
      }
      float v = ps;
      v += __shfl_xor(v, 1); v += __shfl_xor(v, 2);
      v += __shfl_xor(v, 4); v += __shfl_xor(v, 8);
      if (l15 == 0) atomicAdd(&lsum[bh * Tn + row], v);
    }
  }
}

// ---------------------------------------------------------------------------
// Attention pass 2 (fused): per (m-tile, bh), loop n-tiles 0..mt:
// recompute S = QK^T, P = exp(S/8)/l (causal), write normalized wei ONCE,
// accumulate O = P@V in registers via LDS P tile. 512 threads, 8 waves,
// dbuf K/V staging with counted vmcnt. grid: (16, 1, 32).
// ---------------------------------------------------------------------------
__launch_bounds__(512, 2)
__global__ void attn_fused(const u16* __restrict__ qkv, const u16* __restrict__ vT,
                           const float* __restrict__ lsum, float* __restrict__ wei,
                           u16* __restrict__ attn_out) {
  const int bh = blockIdx.z, b = bh >> 4, h = bh & 15;
  const int xm = blockIdx.x;
  const int mt = (xm & 1) ? (15 - (xm >> 1)) : (xm >> 1);   // load-balance remap
  const int m0 = mt << 7;
  float* weib = wei + (size_t)bh * Tn * Tn;
  const u16* qb = qkv + (size_t)b * Tn * 3072 + h * 64;
  const u16* kb = qb + 1024;
  const u16* vtb = vT + (size_t)bh * 64 * Tn;

  __shared__ __align__(16) u16 Ks[2][128 * 64];
  __shared__ __align__(16) u16 Vs[2][64 * 128];
  __shared__ __align__(16) u16 Ps[128 * 128];   // also Q staging area

  const int tid = threadIdx.x;
  const int lane = tid & 63, l15 = lane & 15, quad = lane >> 4;
  const int w = tid >> 6;                 // 0..7
  const int rm = w >> 2, cn = w & 3;      // S wave-grid: rows rm*64, cols cn*32
  const int pm = w >> 1, pc = w & 1;      // PV wave-grid: rows pm*32, cols pc*32

  const int rk = tid >> 3, ck = (tid & 7) << 3;    // K/Q staging: 64 rows/issue
  const int rv = tid >> 4, cv = (tid & 15) << 3;   // V staging: 32 rows/issue
  const int cks = ck ^ ((rk & 7) << 3);            // pre-swizzled source cols
  const int cvs = cv ^ ((rv & 7) << 3);

  auto STAGE = [&](int buf, int nt) {
    const int n0 = nt << 7;
    gload_lds16(&kb[(size_t)(n0 + rk) * 3072 + cks], &Ks[buf][rk * 64 + ck]);
    gload_lds16(&kb[(size_t)(n0 + 64 + rk) * 3072 + cks], &Ks[buf][(64 + rk) * 64 + ck]);
    gload_lds16(&vtb[(size_t)rv * Tn + n0 + cvs], &Vs[buf][rv * 128 + cv]);
    gload_lds16(&vtb[(size_t)(32 + rv) * Tn + n0 + cvs], &Vs[buf][(32 + rv) * 128 + cv]);
  };

  // prologue: Q into Ps area, then K/V tiles 0 and 1
  gload_lds16(&qb[(size_t)(m0 + rk) * 3072 + cks], &Ps[rk * 64 + ck]);
  gload_lds16(&qb[(size_t)(m0 + 64 + rk) * 3072 + cks], &Ps[(64 + rk) * 64 + ck]);
  STAGE(0, 0);
  if (mt >= 1) {
    STAGE(1, 1);
    asm volatile("s_waitcnt vmcnt(8)" ::: "memory");   // Q landed
  } else {
    asm volatile("s_waitcnt vmcnt(4)" ::: "memory");
  }
  __builtin_amdgcn_s_barrier();
  __builtin_amdgcn_sched_barrier(0);

  short8 af[4][2];
#pragma unroll
  for (int i = 0; i < 4; ++i)
#pragma unroll
    for (int ks = 0; ks < 2; ++ks) {
      const int qr = rm * 64 + i * 16 + l15;
      af[i][ks] = *(const short8*)&Ps[qr * 64 + ((ks * 32 + quad * 8) ^ ((qr & 7) << 3))];
    }
  asm volatile("s_waitcnt lgkmcnt(0)" ::: "memory");
  __builtin_amdgcn_sched_barrier(0);
  __builtin_amdgcn_s_barrier();          // Q reads done before Ps overwrite
  __builtin_amdgcn_sched_barrier(0);

  float inv[4][4];
#pragma unroll
  for (int i = 0; i < 4; ++i)
#pragma unroll
    for (int r = 0; r < 4; ++r)
      inv[i][r] = 1.f / lsum[bh * Tn + m0 + rm * 64 + i * 16 + quad * 4 + r];

  floatx4 acc_o[2][2] = {};
  for (int nt = 0; nt <= mt; ++nt) {
    const int cbuf = nt & 1;
    if (nt < mt) asm volatile("s_waitcnt vmcnt(4)" ::: "memory");
    else         asm volatile("s_waitcnt vmcnt(0)" ::: "memory");
    __builtin_amdgcn_s_barrier();        // K/V(nt) resident for all waves
    __builtin_amdgcn_sched_barrier(0);

    // S = Q K^T on this tile
    floatx4 acc_s[4][2] = {};
#pragma unroll
    for (int ks = 0; ks < 2; ++ks) {
      short8 bk[2];
#pragma unroll
      for (int j = 0; j < 2; ++j) {
        const int kr = cn * 32 + j * 16 + l15;
        bk[j] = *(const short8*)&Ks[cbuf][kr * 64 + ((ks * 32 + quad * 8) ^ ((kr & 7) << 3))];
      }
#pragma unroll
      for (int i = 0; i < 4; ++i)
#pragma unroll
        for (int j = 0; j < 2; ++j)
          acc_s[i][j] = __builtin_amdgcn_mfma_f32_16x16x32_bf16(af[i][ks], bk[j], acc_s[i][j], 0, 0, 0);
    }

    // P = exp(S/8)*inv (causal) -> wei (fp32, normalized) + Ps (bf16, swizzled)
    const int n0 = nt << 7;
#pragma unroll
    for (int i = 0; i < 4; ++i)
#pragma unroll
      for (int j = 0; j < 2; ++j)
#pragma unroll
        for (int r = 0; r < 4; ++r) {
          const int prow = rm * 64 + i * 16 + quad * 4 + r;
          const int pcol = cn * 32 + j * 16 + l15;
          const int row = m0 + prow, col = n0 + pcol;
          float p = (col <= row) ? __expf(acc_s[i][j][r] * 0.125f) * inv[i][r] : 0.f;
          weib[(size_t)row * Tn + col] = p;
          Ps[prow * 128 + (pcol ^ ((prow & 7) << 3))] = f2bf(p);
        }
    asm volatile("s_waitcnt lgkmcnt(0)" ::: "memory");
    __builtin_amdgcn_s_barrier();        // Ps complete; Ks[cbuf] consumed
    __builtin_amdgcn_sched_barrier(0);

    // O += P @ V
#pragma unroll
    for (int k = 0; k < 4; ++k) {
      short8 pa[2], vb[2];
#pragma unroll
      for (int i2 = 0; i2 < 2; ++i2) {
        const int pr = pm * 32 + i2 * 16 + l15;
        pa[i2] = *(const short8*)&Ps[pr * 128 + ((k * 32 + quad * 8) ^ ((pr & 7) << 3))];
      }
#pragma unroll
      for (int j2 = 0; j2 < 2; ++j2) {
        const int vr = pc * 32 + j2 * 16 + l15;
        vb[j2] = *(const short8*)&Vs[cbuf][vr * 128 + ((k * 32 + quad * 8) ^ ((vr & 7) << 3))];
      }
#pragma unroll
      for (int i2 = 0; i2 < 2; ++i2)
#pragma unroll
        for (int j2 = 0; j2 < 2; ++j2)
          acc_o[i2][j2] = __builtin_amdgcn_mfma_f32_16x16x32_bf16(pa[i2], vb[j2], acc_o[i2][j2], 0, 0, 0);
    }
    __builtin_amdgcn_s_barrier();        // Ps, Vs[cbuf] consumed
    __builtin_amdgcn_sched_barrier(0);
    if (nt + 2 <= mt) STAGE(cbuf, nt + 2);
  }

  // write O (bf16) in head-concat layout
#pragma unroll
  for (int i2 = 0; i2 < 2; ++i2)
#pragma unroll
    for (int j2 = 0; j2 < 2; ++j2)
#pragma unroll
      for (int r = 0; r < 4; ++r) {
        const int row = m0 + pm * 32 + i2 * 16 + quad * 4 + r;
        const int col = pc * 32 + j2 * 16 + l15;
        attn_out[(size_t)(b * Tn + row) * En + h * 64 + col] = f2bf(acc_o[i2][j2][r]);
      }
}

// ---------------------------------------------------------------------------
// 64x64-tiled transpose fp32 -> bf16: out[C][R] = bf16(in[R][C]^T).
// ---------------------------------------------------------------------------
__global__ void transpose_wf(const float* __restrict__ in, u16* __restrict__ out, int R, int Cc) {
  __shared__ u16 t[64][65];
  const int tid = threadIdx.x;
  const int r0 = blockIdx.y << 6, c0 = blockIdx.x << 6;
#pragma unroll
  for (int it = 0; it < 4; ++it) {
    int lin = it * 256 + tid;
    int r = lin >> 4, c4 = (lin & 15) << 2;
    float4 v = *(const float4*)&in[(size_t)(r0 + r) * Cc + c0 + c4];
    t[r][c4 + 0] = f2bf(v.x); t[r][c4 + 1] = f2bf(v.y);
    t[r][c4 + 2] = f2bf(v.z); t[r][c4 + 3] = f2bf(v.w);
  }
  __syncthreads();
#pragma unroll
  for (int it = 0; it < 2; ++it) {
    int lin = it * 256 + tid;
    int r = lin >> 3, cc = (lin & 7) << 3;
    u16 t8[8];
#pragma unroll
    for (int e = 0; e < 8; ++e) t8[e] = t[cc + e][r];
    *(uint4*)&out[(size_t)(c0 + r) * R + r0 + cc] = *(uint4*)t8;
  }
}

// wq/wk/wv fp32 [16][1024][64] -> bf16 WqkvT [3072][1024]
__global__ void repack_qkvw(const float* __restrict__ wq, const float* __restrict__ wk,
                            const float* __restrict__ wv, u16* __restrict__ out) {
  const int which = blockIdx.z;
  const float* w = which == 0 ? wq : (which == 1 ? wk : wv);
  const int h = blockIdx.y;
  const int e0 = blockIdx.x << 6;
  __shared__ u16 t[64][65];
  const int tid = threadIdx.x;
  const float* ib = w + (size_t)h * 1024 * 64;
#pragma unroll
  for (int it = 0; it < 4; ++it) {
    int lin = it * 256 + tid;
    int r = lin >> 4, c4 = (lin & 15) << 2;
    float4 v = *(const float4*)&ib[(size_t)(e0 + r) * 64 + c4];
    t[r][c4 + 0] = f2bf(v.x); t[r][c4 + 1] = f2bf(v.y);
    t[r][c4 + 2] = f2bf(v.z); t[r][c4 + 3] = f2bf(v.w);
  }
  __syncthreads();
  u16* ob = out + ((size_t)which * 1024 + h * 64) * 1024;
#pragma unroll
  for (int it = 0; it < 2; ++it) {
    int lin = it * 256 + tid;
    int r = lin >> 3, cc = (lin & 7) << 3;
    u16 t8[8];
#pragma unroll
    for (int e = 0; e < 8; ++e) t8[e] = t[cc + e][r];
    *(uint4*)&ob[(size_t)r * 1024 + e0 + cc] = *(uint4*)t8;
  }
}

// v slice of qkv (bf16) -> vT [bh][64][T] (bf16)
__global__ void transpose_v(const u16* __restrict__ qkv, u16* __restrict__ vT) {
  const int bh = blockIdx.z, b = bh >> 4, h = bh & 15;
  const int s0 = blockIdx.x << 6;
  __shared__ u16 t[64][65];
  const int tid = threadIdx.x;
  const u16* ib = qkv + (size_t)b * Tn * 3072 + 2048 + h * 64;
#pragma unroll
  for (int it = 0; it < 2; ++it) {
    int lin = it * 256 + tid;
    int r = lin >> 3, cc = (lin & 7) << 3;
    uint4 v = *(const uint4*)&ib[(size_t)(s0 + r) * 3072 + cc];
    u16 t8[8]; *(uint4*)t8 = v;
#pragma unroll
    for (int e = 0; e < 8; ++e) t[r][cc + e] = t8[e];
  }
  __syncthreads();
  u16* ob = vT + (size_t)bh * 64 * Tn;
#pragma unroll
  for (int it = 0; it < 2; ++it) {
    int lin = it * 256 + tid;
    int r = lin >> 3, cc = (lin & 7) << 3;
    u16 t8[8];
#pragma unroll
    for (int e = 0; e < 8; ++e) t8[e] = t[cc + e][r];
    *(uint4*)&ob[(size_t)r * Tn + s0 + cc] = *(uint4*)t8;
  }
}

// fp32 in, fp32 params, bf16 out (GEMM operand)
__launch_bounds__(256)
__global__ void layernorm_k(const float* __restrict__ x, const float* __restrict__ g,
                            const float* __restrict__ be, u16* __restrict__ out) {
  const int row = blockIdx.x;
  const int tid = threadIdx.x;
  const float* xr = x + (size_t)row * En;
  float4 xv = *(const float4*)&xr[tid * 4];
  float s = xv.x + xv.y + xv.z + xv.w;
  float sq = xv.x * xv.x + xv.y * xv.y + xv.z * xv.z + xv.w * xv.w;
#pragma unroll
  for (int o = 1; o < 64; o <<= 1) { s += __shfl_xor(s, o); sq += __shfl_xor(sq, o); }
  __shared__ float red[8];
  const int wave = tid >> 6, lane = tid & 63;
  if (lane == 0) { red[wave] = s; red[wave + 4] = sq; }
  __syncthreads();
  const float S  = red[0] + red[1] + red[2] + red[3];
  const float SQ = red[4] + red[5] + red[6] + red[7];
  const float mu = S * (1.f / 1024.f);
  const float var = SQ * (1.f / 1024.f) - mu * mu;
  const float rstd = rsqrtf(var + 1e-5f);
  float4 gv = *(const float4*)&g[tid * 4];
  float4 bv = *(const float4*)&be[tid * 4];
  ushort4 ov;
  ov.x = f2bf((xv.x - mu) * rstd * gv.x + bv.x);
  ov.y = f2bf((xv.y - mu) * rstd * gv.y + bv.y);
  ov.z = f2bf((xv.z - mu) * rstd * gv.z + bv.z);
  ov.w = f2bf((xv.w - mu) * rstd * gv.w + bv.w);
  *(ushort4*)&out[(size_t)row * En + tid * 4] = ov;
}

// out(fp32) = val(bf16) + gate(bf16) * res(fp32)
__global__ void gated_residual(const u16* __restrict__ val, const u16* __restrict__ gate,
                               const float* __restrict__ res, float* __restrict__ out) {
  const size_t i = ((size_t)blockIdx.x * 256 + threadIdx.x) * 4;
  ushort4 v = *(const ushort4*)&val[i];
  ushort4 g = *(const ushort4*)&gate[i];
  float4 r = *(const float4*)&res[i];
  float4 o;
  o.x = bf2f(v.x) + bf2f(g.x) * r.x;
  o.y = bf2f(v.y) + bf2f(g.y) * r.y;
  o.z = bf2f(v.z) + bf2f(g.z) * r.z;
  o.w = bf2f(v.w) + bf2f(g.w) * r.w;
  *(float4*)&out[i] = o;
}

extern "C" void kernel_launch(void* const* d_in, const int* in_sizes, int n_in,
                              void* d_out, int out_size, void* d_ws, size_t ws_size,
                              hipStream_t stream) {
  const float* x    = (const float*)d_in[0];
  const float* wq   = (const float*)d_in[1];
  const float* wk   = (const float*)d_in[2];
  const float* wv   = (const float*)d_in[3];
  const float* wp   = (const float*)d_in[4];
  const float* bp   = (const float*)d_in[5];
  const float* ln1g = (const float*)d_in[6];
  const float* ln1b = (const float*)d_in[7];
  const float* ln2g = (const float*)d_in[8];
  const float* ln2b = (const float*)d_in[9];
  const float* w1   = (const float*)d_in[10];
  const float* b1   = (const float*)d_in[11];
  const float* w2   = (const float*)d_in[12];
  const float* b2   = (const float*)d_in[13];
  const float* w3   = (const float*)d_in[14];
  const float* b3   = (const float*)d_in[15];
  const float* wga  = (const float*)d_in[16];
  const float* bga  = (const float*)d_in[17];
  const float* wgf  = (const float*)d_in[18];
  const float* bgf  = (const float*)d_in[19];

  float* out_x = (float*)d_out;
  float* wei   = out_x + (size_t)BTn * En;   // output 1, [B,H,T,T] fp32

  char* wsb = (char*)d_ws;
  size_t off = 0;
  auto alloc = [&](size_t bytes) { char* p = wsb + off; off += (bytes + 255) & ~(size_t)255; return p; };
  float* lsum = (float*)alloc((size_t)32 * Tn * 4);
  u16* WqkvT = (u16*)alloc((size_t)3072 * 1024 * 2);
  u16* wpT   = (u16*)alloc((size_t)1024 * 1024 * 2);
  u16* wgaT  = (u16*)alloc((size_t)1024 * 1024 * 2);
  u16* w1T   = (u16*)alloc((size_t)4096 * 1024 * 2);
  u16* w2T   = (u16*)alloc((size_t)2048 * 4096 * 2);
  u16* w3T   = (u16*)alloc((size_t)1024 * 2048 * 2);
  u16* wgfT  = (u16*)alloc((size_t)1024 * 1024 * 2);
  u16* h1    = (u16*)alloc((size_t)BTn * En * 2);      // aliased: h2, g2 later
  u16* qkv   = (u16*)alloc((size_t)BTn * 3072 * 2);    // aliased: f1 start
  u16* vT    = (u16*)alloc((size_t)32 * 64 * Tn * 2);  // aliased: f1 tail
  u16* attn  = (u16*)alloc((size_t)BTn * En * 2);      // aliased: f2 start
  u16* sa    = (u16*)alloc((size_t)BTn * En * 2);      // aliased: f2 tail
  u16* glin  = (u16*)alloc((size_t)BTn * En * 2);      // aliased: f3
  float* x1  = (float*)alloc((size_t)BTn * En * 4);    // fp32 residual stream
  u16* h2 = h1;      // h1 dead after qkv GEMM
  u16* f1 = qkv;     // 32MB = qkv(24MB)+vT(8MB), both dead by then
  u16* f2 = attn;    // 16MB = attn(8MB)+sa(8MB), both dead by then
  u16* f3 = glin;    // glin dead after gated_residual #1
  u16* g2 = h1;      // h1 dead after ff1 GEMM

  hipMemsetAsync(lsum, 0, (size_t)32 * Tn * 4, stream);
  repack_qkvw<<<dim3(16, 16, 3), 256, 0, stream>>>(wq, wk, wv, WqkvT);
  transpose_wf<<<dim3(16, 16), 256, 0, stream>>>(wp,  wpT,  1024, 1024);
  transpose_wf<<<dim3(16, 16), 256, 0, stream>>>(wga, wgaT, 1024, 1024);
  transpose_wf<<<dim3(64, 16), 256, 0, stream>>>(w1,  w1T,  1024, 4096);
  transpose_wf<<<dim3(32, 64), 256, 0, stream>>>(w2,  w2T,  4096, 2048);
  transpose_wf<<<dim3(16, 32), 256, 0, stream>>>(w3,  w3T,  2048, 1024);
  transpose_wf<<<dim3(16, 16), 256, 0, stream>>>(wgf, wgfT, 1024, 1024);

  layernorm_k<<<BTn, 256, 0, stream>>>(x, ln1g, ln1b, h1);
  gemm_bt<0><<<dim3(24, 32), 256, 0, stream>>>(h1, WqkvT, nullptr, qkv, BTn, 3072, 1024);
  transpose_v<<<dim3(32, 1, 32), 256, 0, stream>>>(qkv, vT);
  attn_rowsum<<<dim3(16, 16, 32), 256, 0, stream>>>(qkv, wei, lsum);
  attn_fused<<<dim3(16, 1, 32), 512, 0, stream>>>(qkv, vT, lsum, wei, attn);
  gemm_bt<0><<<dim3(8, 32), 256, 0, stream>>>(attn, wpT, bp, sa, BTn, 1024, 1024);
  gemm_bt<2><<<dim3(8, 32), 256, 0, stream>>>(sa, wgaT, bga, glin, BTn, 1024, 1024);
  gated_residual<<<BTn, 256, 0, stream>>>(sa, glin, x, x1);
  layernorm_k<<<BTn, 256, 0, stream>>>(x1, ln2g, ln2b, h2);
  gemm_bt<1><<<dim3(32, 32), 256, 0, stream>>>(h2, w1T, b1, f1, BTn, 4096, 1024);
  gemm_bt<1><<<dim3(16, 32), 256, 0, stream>>>(f1, w2T, b2, f2, BTn, 2048, 4096);
  gemm_bt<0><<<dim3(8, 32), 256, 0, stream>>>(f2, w3T, b3, f3, BTn, 1024, 2048);
  gemm_bt<2><<<dim3(8, 32), 256, 0, stream>>>(f3, wgfT, bgf, g2, BTn, 1024, 1024);
  gated_residual<<<BTn, 256, 0, stream>>>(f3, g2, x1, out_x);
}